// Round 17
// baseline (247.767 us; speedup 1.0000x reference)
//
#include <hip/hip_runtime.h>
#include <hip/hip_bf16.h>

// ---------------------------------------------------------------------------
// NCP model: conv head + FC + LTC recurrence.
// Round 16: single isolated change vs R15 — LTC's __shfl broadcast replaced
//           by v_readlane (wave-uniform index -> SGPR, removes 64 of 136
//           DS-pipe ops per unfold per CU; DS-pipe is the counted
//           bottleneck). Everything else byte-identical to R15 (245.5us).
// ---------------------------------------------------------------------------

typedef _Float16 f16;
typedef _Float16 f16x8 __attribute__((ext_vector_type(8)));
typedef _Float16 f16x4 __attribute__((ext_vector_type(4)));
typedef float    f32x4 __attribute__((ext_vector_type(4)));
typedef unsigned int u32;

static __device__ __forceinline__ float sigmoidf_fast(float x) {
    return __builtin_amdgcn_rcpf(1.0f + __expf(-x));
}

// async 16B global->LDS: LDS dest must be wave-uniform base + lane*16.
static __device__ __forceinline__ void gload_lds16(const void* g, void* l) {
    __builtin_amdgcn_global_load_lds(
        (const __attribute__((address_space(1))) void*)g,
        (__attribute__((address_space(3))) void*)l, 16, 0, 0);
}

// ---------------------------------------------------------------------------
// h1T layout: [512][31 rows][296 slots][8 halves] f16 (rows of 98 cols, 3 c8):
//   slot(w,c8) = c8*98 + (w&1)*49 + (w>>1)
// h2f layout: [512][14 rows][241 slots][8 halves] f16 (47 cols, 5 c8):
//   slot(w,c8) = c8*47 + (w&1)*24 + (w>>1)
// ---------------------------------------------------------------------------

// All three weight packs in one launch.
__global__ __launch_bounds__(256)
void wpack_all(const float* __restrict__ w1, f16* __restrict__ Wpk1,
               const float* __restrict__ w2, f16* __restrict__ Wpk,
               const float* __restrict__ w3, f16* __restrict__ Wpk3)
{
    int bx = blockIdx.x;
    if (bx < 17) {
        int idx = bx * 256 + threadIdx.x;
        if (idx >= 32 * 136) return;
        int co = idx / 136, kk = idx % 136;
        float v = 0.0f;
        if (co < 24 && kk < 120) {
            int p = kk >> 3, jj = kk & 7;
            int kh = p / 3, kwp = p % 3;
            int kws = jj >> 2, ci = jj & 3;
            int kw = 2 * kwp + kws;
            if (kw < 5 && ci < 3)
                v = w1[(((size_t)co * 3 + ci) * 5 + kh) * 5 + kw];
        }
        Wpk1[idx] = (f16)v;
    } else if (bx < 133) {
        int idx = (bx - 17) * 256 + threadIdx.x;
        if (idx >= 48 * 616) return;
        int co = idx / 616, kk = idx % 616;
        float v = 0.0f;
        if (kk < 608 && co < 36) {
            int c = kk >> 3, j = kk & 7;
            if (c < 75) {
                int pq = c / 3, c8 = c - 3 * pq;
                int kh = pq / 5, kw = pq - 5 * kh;
                int ci = c8 * 8 + j;
                v = w2[(((size_t)co * 24 + ci) * 5 + kh) * 5 + kw];
            }
        }
        Wpk[idx] = (f16)v;
    } else {
        int idx = (bx - 133) * 256 + threadIdx.x;
        if (idx >= 48 * 1032) return;
        int co = idx / 1032, kk = idx % 1032;
        float v = 0.0f;
        if (kk < 1024) {
            int c = kk >> 3, j = kk & 7;
            int pq = c / 5, c8 = c - 5 * pq;
            if (pq < 25) {
                int kh = pq / 5, kw = pq - 5 * kh;
                int ci = c8 * 8 + j;
                if (ci < 36)
                    v = w3[(((size_t)co * 36 + ci) * 5 + kh) * 5 + kw];
            }
        }
        Wpk3[idx] = (f16)v;
    }
}

// conv1 via MFMA: 2 blocks per image (ho halves). Staged rows [35][200][ci4]
// f16 in LDS (56 KB -> 2 blocks/CU). Weights in registers from global.
__global__ __launch_bounds__(512)
void conv1_mfma(const float* __restrict__ x, const f16* __restrict__ Wpk1,
                const float* __restrict__ b1, f16* __restrict__ h1T)
{
    __shared__ __align__(16) f16 img[35 * 200 * 4];   // 56,000 B

    int blk  = blockIdx.x;
    int m    = blk >> 1;
    int hf   = blk & 1;
    int tid  = threadIdx.x;
    int lane = tid & 63;
    int wv   = tid >> 6;        // 0..7
    int col  = lane & 15;
    int row4 = lane >> 4;

    int ho_base = hf * 16;
    int r0      = 2 * ho_base;
    int nrows   = hf ? 33 : 35;
    int nho     = hf ? 15 : 16;
    int npx     = nho * 98;
    int ntile   = (npx + 15) >> 4;
    int niter   = (ntile + 7) >> 3;

    // stage: batched preload, all loads in flight before writes
    {
        const float* p0 = x + (size_t)m * 39600 + (size_t)r0 * 200;
        int n4 = (nrows * 200) >> 2;
        float4 ra[4], rb[4], rc[4];
        #pragma unroll
        for (int k = 0; k < 4; ++k) {
            int u4 = tid + k * 512;
            if (u4 < n4) {
                ra[k] = *(const float4*)(p0 + (size_t)u4 * 4);
                rb[k] = *(const float4*)(p0 + 13200 + (size_t)u4 * 4);
                rc[k] = *(const float4*)(p0 + 26400 + (size_t)u4 * 4);
            }
        }
        #pragma unroll
        for (int k = 0; k < 4; ++k) {
            int u4 = tid + k * 512;
            if (u4 < n4) {
                float4 a = ra[k], b = rb[k], c = rc[k];
                f16x8 lo = { (f16)a.x, (f16)b.x, (f16)c.x, (f16)0.0f,
                             (f16)a.y, (f16)b.y, (f16)c.y, (f16)0.0f };
                f16x8 hi = { (f16)a.z, (f16)b.z, (f16)c.z, (f16)0.0f,
                             (f16)a.w, (f16)b.w, (f16)c.w, (f16)0.0f };
                *(f16x8*)(&img[(size_t)u4 * 16])     = lo;
                *(f16x8*)(&img[(size_t)u4 * 16 + 8]) = hi;
            }
        }
    }

    f16x8 af[2][4];
    #pragma unroll
    for (int Mt = 0; Mt < 2; ++Mt)
        #pragma unroll
        for (int t = 0; t < 4; ++t)
            af[Mt][t] = *(const f16x8*)((const char*)Wpk1 +
                           (Mt * 16 + col) * 272 + t * 64 + row4 * 16);

    int rowB[4], kwpv[4];
    #pragma unroll
    for (int t = 0; t < 4; ++t) {
        int p = 4 * t + row4; if (p > 14) p = 14;
        rowB[t] = (p / 3) * 1600;
        kwpv[t] = (p % 3) * 16;
    }

    float bvv[2][4];
    #pragma unroll
    for (int Mt = 0; Mt < 2; ++Mt)
        #pragma unroll
        for (int i = 0; i < 4; ++i) {
            int co = Mt * 16 + row4 * 4 + i;
            bvv[Mt][i] = (co < 24) ? b1[co] : 0.0f;
        }

    __syncthreads();

    const char* ic = (const char*)img;
    for (int it = 0; it < niter; ++it) {
        int s = wv + it * 8;
        if (s >= ntile) continue;
        int px = s * 16 + col;
        bool pv = (px < npx);
        int pc = pv ? px : npx - 1;
        int ho_l = pc / 98;
        int wo   = pc - ho_l * 98;
        int base = ho_l * 3200 + wo * 16;

        f32x4 a0 = {0.f,0.f,0.f,0.f}, a1 = {0.f,0.f,0.f,0.f};
        #pragma unroll
        for (int t = 0; t < 4; ++t) {
            f16x8 xf = *(const f16x8*)(ic + base + rowB[t] + kwpv[t]);
            a0 = __builtin_amdgcn_mfma_f32_16x16x32_f16(af[0][t], xf, a0, 0, 0, 0);
            a1 = __builtin_amdgcn_mfma_f32_16x16x32_f16(af[1][t], xf, a1, 0, 0, 0);
        }

        if (pv) {
            int ho = ho_base + ho_l;
            size_t rowbase = ((size_t)m * 31 + ho) * 296;
            int par = (wo & 1) * 49, wh = wo >> 1;
            int j0 = (row4 & 1) * 4;
            {
                int c8 = row4 >> 1;
                f16x4 pk = { (f16)fmaxf(a0[0] + bvv[0][0], 0.0f),
                             (f16)fmaxf(a0[1] + bvv[0][1], 0.0f),
                             (f16)fmaxf(a0[2] + bvv[0][2], 0.0f),
                             (f16)fmaxf(a0[3] + bvv[0][3], 0.0f) };
                int sl = c8 * 98 + par + wh;
                *(f16x4*)(h1T + (rowbase + sl) * 8 + j0) = pk;
            }
            if (row4 < 2) {
                f16x4 pk = { (f16)fmaxf(a1[0] + bvv[1][0], 0.0f),
                             (f16)fmaxf(a1[1] + bvv[1][1], 0.0f),
                             (f16)fmaxf(a1[2] + bvv[1][2], 0.0f),
                             (f16)fmaxf(a1[3] + bvv[1][3], 0.0f) };
                int sl = 2 * 98 + par + wh;
                *(f16x4*)(h1T + (rowbase + sl) * 8 + j0) = pk;
            }
        }
    }
}

// conv2 via MFMA: block = one image, whole image in LDS via async
// global_load_lds. A in registers; B parity layout.
__global__ __launch_bounds__(384)
void conv2_mfma(const f16* __restrict__ h1T, const f16* __restrict__ Wpk,
                const float* __restrict__ b2, f16* __restrict__ h2f)
{
    __shared__ __align__(16) f16 img[9216 * 8];   // 147,456 B (9176 used)
    __shared__ u32 lutS[76];

    int m    = blockIdx.x;
    int tid  = threadIdx.x;
    int lane = tid & 63;
    int wv   = tid >> 6;
    int ct   = wv >> 1;
    int sh   = wv & 1;
    int row4 = lane >> 4;
    int col  = lane & 15;

    {
        const char* g = (const char*)(h1T + (size_t)m * 73408);
        char* l = (char*)img;
        #pragma unroll
        for (int k = 0; k < 24; ++k) {
            int u0 = wv * 64 + k * 384;
            gload_lds16(g + ((size_t)(u0 + lane)) * 16, l + (size_t)u0 * 16);
        }
    }

    if (tid < 76) {
        int c = tid; u32 v = 0;
        if (c < 75) {
            int pq = c / 3, c8 = c - 3 * pq;
            int kh = pq / 5, kw = pq - 5 * kh;
            u32 ofs = (u32)(c8 * 98 + (kw & 1) * 49 + (kw >> 1));
            v = ((u32)(kh * 4736) << 8) | ofs;
        }
        lutS[c] = v;
    }

    f16x8 af[19];
    {
        const char* wb = (const char*)Wpk + (size_t)(ct * 16 + col) * 1232 + row4 * 16;
        #pragma unroll
        for (int t = 0; t < 19; ++t)
            af[t] = *(const f16x8*)(wb + t * 64);
    }

    float bv[4];
    #pragma unroll
    for (int i = 0; i < 4; ++i) {
        int co = ct * 16 + row4 * 4 + i;
        bv[i] = (co < 36) ? b2[co] : 0.0f;
    }
    int c8o  = ct * 2 + (row4 >> 1);
    int hsel = (row4 & 1) * 4;

    __syncthreads();

    const char* ic = (const char*)img;
    for (int it = 0; it < 7; ++it) {
        int rbase[3], valid[3], hov[3], wov[3];
        #pragma unroll
        for (int si = 0; si < 3; ++si) {
            int tile = sh * 21 + it * 3 + si;
            int px   = tile * 16 + col;
            valid[si] = (px < 658);
            int pc = valid[si] ? px : 657;
            int ho = pc / 47;
            int wo = pc - 47 * ho;
            rbase[si] = ho * 9472 + wo * 16;
            hov[si] = ho; wov[si] = wo;
        }

        f32x4 acc0 = {0.f,0.f,0.f,0.f}, acc1 = {0.f,0.f,0.f,0.f}, acc2 = {0.f,0.f,0.f,0.f};
        #pragma unroll
        for (int t = 0; t < 19; ++t) {
            u32 lv   = lutS[4 * t + row4];
            int rowb = (int)(lv >> 8);
            int boff = (int)(lv & 255) << 4;
            f16x8 a = af[t];
            {
                f16x8 xf = *(const f16x8*)(ic + rbase[0] + rowb + boff);
                acc0 = __builtin_amdgcn_mfma_f32_16x16x32_f16(a, xf, acc0, 0, 0, 0);
            }
            {
                f16x8 xf = *(const f16x8*)(ic + rbase[1] + rowb + boff);
                acc1 = __builtin_amdgcn_mfma_f32_16x16x32_f16(a, xf, acc1, 0, 0, 0);
            }
            {
                f16x8 xf = *(const f16x8*)(ic + rbase[2] + rowb + boff);
                acc2 = __builtin_amdgcn_mfma_f32_16x16x32_f16(a, xf, acc2, 0, 0, 0);
            }
        }

        #pragma unroll
        for (int si = 0; si < 3; ++si) {
            f32x4 a = (si == 0) ? acc0 : (si == 1) ? acc1 : acc2;
            if (valid[si] && c8o < 5) {
                int wo = wov[si], ho = hov[si];
                f16x4 pk;
                #pragma unroll
                for (int i = 0; i < 4; ++i) pk[i] = (f16)fmaxf(a[i] + bv[i], 0.0f);
                int sl = c8o * 47 + (wo & 1) * 24 + (wo >> 1);
                *(f16x4*)(h2f + ((size_t)m * 3374 + (size_t)ho * 241 + sl) * 8 + hsel) = pk;
            }
        }
    }
}

// conv3 via MFMA: whole image + weights in LDS via async global_load_lds.
__global__ __launch_bounds__(384)
void conv3_mfma(const f16* __restrict__ h2f, const f16* __restrict__ Wpk3,
                const float* __restrict__ b3, float* __restrict__ h3)
{
    __shared__ __align__(16) f16 Wl[6208 * 8];    // 99,328 B (99,072 used)
    __shared__ __align__(16) f16 img[3392 * 8];   // 54,272 B (53,984 used)
    __shared__ u32 lut[128];

    int m    = blockIdx.x;
    int tid  = threadIdx.x;
    int lane = tid & 63;
    int wv   = tid >> 6;
    int ct   = wv >> 1;
    int sh   = wv & 1;
    int row4 = lane >> 4;
    int col  = lane & 15;

    {
        const char* g = (const char*)Wpk3;
        char* l = (char*)Wl;
        #pragma unroll
        for (int k = 0; k < 17; ++k) {
            int u0 = wv * 64 + k * 384;
            if (u0 < 6208)
                gload_lds16(g + ((size_t)(u0 + lane)) * 16, l + (size_t)u0 * 16);
        }
    }
    {
        const char* g = (const char*)(h2f + (size_t)m * 3374 * 8);
        char* l = (char*)img;
        #pragma unroll
        for (int k = 0; k < 9; ++k) {
            int u0 = wv * 64 + k * 384;
            if (u0 < 3392)
                gload_lds16(g + ((size_t)(u0 + lane)) * 16, l + (size_t)u0 * 16);
        }
    }

    if (tid < 128) {
        int c  = tid;
        int pq = c / 5, c8 = c - 5 * pq;
        int kh = pq / 5, kw = pq - 5 * kh;
        lut[c] = ((u32)(kh * 3856) << 8) |
                 (u32)(c8 * 47 + (kw & 1) * 24 + (kw >> 1));
    }

    int rb[4], wo16[4], valid[4], hov[4], wov[4];
    int nsi = 4 - sh;
    #pragma unroll
    for (int si = 0; si < 4; ++si) {
        int s  = 4 * sh + si;
        int px = 16 * s + col;
        valid[si] = (si < nsi) && (px < 110);
        int pc = px < 110 ? px : 109;
        int ho = pc / 22, wo = pc - 22 * ho;
        rb[si]   = ho * 7712;
        wo16[si] = wo * 16;
        hov[si]  = ho; wov[si] = wo;
    }

    float bv[4];
    #pragma unroll
    for (int i = 0; i < 4; ++i) bv[i] = b3[ct * 16 + row4 * 4 + i];

    __syncthreads();

    int Abase = (ct * 16 + col) * 2064 + row4 * 16;
    const char* Wc = (const char*)Wl;
    const char* ic = (const char*)img;

    f32x4 a0 = {0.f,0.f,0.f,0.f}, a1 = {0.f,0.f,0.f,0.f};
    f32x4 a2 = {0.f,0.f,0.f,0.f}, a3 = {0.f,0.f,0.f,0.f};
    #pragma unroll 8
    for (int t = 0; t < 32; ++t) {
        u32 lv     = lut[4 * t + row4];
        int rowoff = (int)(lv >> 8);
        int boff   = (int)(lv & 255) << 4;
        f16x8 af = *(const f16x8*)(Wc + Abase + 64 * t);
        {
            f16x8 xf = *(const f16x8*)(ic + rb[0] + rowoff + boff + wo16[0]);
            a0 = __builtin_amdgcn_mfma_f32_16x16x32_f16(af, xf, a0, 0, 0, 0);
        }
        {
            f16x8 xf = *(const f16x8*)(ic + rb[1] + rowoff + boff + wo16[1]);
            a1 = __builtin_amdgcn_mfma_f32_16x16x32_f16(af, xf, a1, 0, 0, 0);
        }
        {
            f16x8 xf = *(const f16x8*)(ic + rb[2] + rowoff + boff + wo16[2]);
            a2 = __builtin_amdgcn_mfma_f32_16x16x32_f16(af, xf, a2, 0, 0, 0);
        }
        {
            f16x8 xf = *(const f16x8*)(ic + rb[3] + rowoff + boff + wo16[3]);
            a3 = __builtin_amdgcn_mfma_f32_16x16x32_f16(af, xf, a3, 0, 0, 0);
        }
    }

    int co0 = ct * 16 + row4 * 4;
    #pragma unroll
    for (int si = 0; si < 4; ++si) {
        if (!valid[si]) continue;
        f32x4 a = (si == 0) ? a0 : (si == 1) ? a1 : (si == 2) ? a2 : a3;
        float* op = h3 + (((size_t)m * 48 + co0) * 5 + hov[si]) * 22 + wov[si];
        #pragma unroll
        for (int i = 0; i < 4; ++i)
            op[(size_t)i * 110] = fmaxf(a[i] + bv[i], 0.0f);
    }
}

// Register-tiled fp32 direct conv for conv4..conv5.
template<int CIN, int KH, int KW, int STRIDE, int CO_T, int WO_T>
__global__ __launch_bounds__(256)
void conv_tile_kernel(const float* __restrict__ in, const float* __restrict__ wt,
                      const float* __restrict__ bias, float* __restrict__ out,
                      int Cout, int Hin, int Win, int Hout, int Wout,
                      int n_cg, int n_wg, int M)
{
    constexpr int LOAD_W = (WO_T - 1) * STRIDE + KW;

    int bx = blockIdx.x;
    int cg = bx % n_cg;
    int gid = (bx / n_cg) * blockDim.x + threadIdx.x;
    int wg = gid % n_wg;
    int t  = gid / n_wg;
    int ho = t % Hout;
    int m  = t / Hout;
    if (m >= M) return;

    int wo0 = wg * WO_T;
    int co0 = cg * CO_T;

    const float* ip = in + ((size_t)(m * CIN) * Hin + (size_t)ho * STRIDE) * Win
                         + (size_t)wo0 * STRIDE;
    const float* wp = wt + (size_t)co0 * (CIN * KH * KW);

    float acc[CO_T][WO_T];
    #pragma unroll
    for (int c = 0; c < CO_T; ++c) {
        float b = bias[co0 + c];
        #pragma unroll
        for (int q = 0; q < WO_T; ++q) acc[c][q] = b;
    }

    #pragma unroll 1
    for (int ci = 0; ci < CIN; ++ci) {
        #pragma unroll
        for (int kh = 0; kh < KH; ++kh) {
            const float* row = ip + ((size_t)ci * Hin + kh) * Win;
            float xv[LOAD_W];
            #pragma unroll
            for (int l = 0; l < LOAD_W; ++l) xv[l] = row[l];
            const float* wrow = wp + (ci * KH + kh) * KW;
            #pragma unroll
            for (int c = 0; c < CO_T; ++c) {
                #pragma unroll
                for (int kw = 0; kw < KW; ++kw) {
                    float wv = wrow[c * (CIN * KH * KW) + kw];
                    #pragma unroll
                    for (int q = 0; q < WO_T; ++q)
                        acc[c][q] = fmaf(xv[q * STRIDE + kw], wv, acc[c][q]);
                }
            }
        }
    }

    #pragma unroll
    for (int c = 0; c < CO_T; ++c) {
        float* op = out + (((size_t)m * Cout + co0 + c) * Hout + ho) * Wout + wo0;
        #pragma unroll
        for (int q = 0; q < WO_T; ++q) {
            if (wo0 + q < Wout) op[q] = fmaxf(acc[c][q], 0.0f);
        }
    }
}

// FC (1152 -> 128) + relu. One frame per block, 8-way split-K, float4 loads.
__global__ __launch_bounds__(256)
void fc_relu_kernel(const float* __restrict__ h, const float* __restrict__ w,
                    const float* __restrict__ b, float* __restrict__ out)
{
    __shared__ float hs[1152];
    __shared__ float part[8][32][4];
    int f   = blockIdx.x;
    int tid = threadIdx.x;
    int ks  = tid >> 5;
    int j4  = tid & 31;
    for (int k = tid; k < 1152; k += 256) hs[k] = h[(size_t)f * 1152 + k];
    __syncthreads();
    const float4* w4 = (const float4*)w;
    float4 acc = {0.f, 0.f, 0.f, 0.f};
    int k0 = ks * 144;
    #pragma unroll 4
    for (int kk = 0; kk < 144; ++kk) {
        int k = k0 + kk;
        float4 wv = w4[(size_t)k * 32 + j4];
        float hb = hs[k];
        acc.x = fmaf(wv.x, hb, acc.x);
        acc.y = fmaf(wv.y, hb, acc.y);
        acc.z = fmaf(wv.z, hb, acc.z);
        acc.w = fmaf(wv.w, hb, acc.w);
    }
    *(float4*)&part[ks][j4][0] = acc;
    __syncthreads();
    if (tid < 128) {
        int j = tid, jq = j >> 2, r = j & 3;
        float s = b[j];
        #pragma unroll
        for (int q = 0; q < 8; ++q) s += part[q][jq][r];
        out[(size_t)f * 128 + j] = fmaxf(s, 0.0f);
    }
}

// Sensory synapse pre-computation.
__global__ __launch_bounds__(64)
void sensory_kernel(const float* __restrict__ feat,
                    const float* __restrict__ s_mu,
                    const float* __restrict__ s_sigma,
                    const float* __restrict__ s_w,
                    const float* __restrict__ s_erev,
                    float* __restrict__ wnum, float* __restrict__ wden)
{
    __shared__ float y[128];
    int bt = blockIdx.x;
    int n  = threadIdx.x;
    for (int s = n; s < 128; s += 64) y[s] = feat[bt * 128 + s];
    __syncthreads();
    float num = 0.0f, den = 0.0f;
    for (int s = 0; s < 128; ++s) {
        int o = s * 64 + n;
        float a = s_w[o] * sigmoidf_fast((y[s] - s_mu[o]) * s_sigma[o]);
        num = fmaf(a, s_erev[o], num);
        den += a;
    }
    wnum[bt * 64 + n] = num;
    wden[bt * 64 + n] = den;
}

// ---------------------------------------------------------------------------
// LTC recurrence: R10's 8-wave structure with ONE change — v_i broadcast via
// v_readlane (wave-uniform index, VALU->SGPR) instead of __shfl
// (ds_bpermute). Removes 64 of the ~136 DS-pipe wave-ops per unfold per CU.
// ---------------------------------------------------------------------------
__global__ __launch_bounds__(512)
void ltc_wave_kernel(const float* __restrict__ wnum_s,
                     const float* __restrict__ wden_s,
                     const float* __restrict__ mu, const float* __restrict__ sigma,
                     const float* __restrict__ w, const float* __restrict__ erev,
                     const float* __restrict__ gleak, const float* __restrict__ vleak,
                     const float* __restrict__ cm, float* __restrict__ out, int T)
{
    __shared__ float2 pnd[2][8][64];

    int b    = blockIdx.x;
    int tid  = threadIdx.x;
    int lane = tid & 63;
    int p    = tid >> 6;

    float musig[8], nsg[8], wvv[8], wev[8];
    #pragma unroll
    for (int ii = 0; ii < 8; ++ii) {
        int o = (8 * p + ii) * 64 + lane;
        float sg = sigma[o];
        musig[ii] = mu[o] * sg;
        nsg[ii]   = -sg;
        float wl  = w[o];
        wvv[ii]   = wl;
        wev[ii]   = wl * erev[o];
    }
    float gl   = gleak[lane];
    float glvl = gl * vleak[lane];
    float cmt  = cm[lane] * 6.0f;
    float v    = 0.0f;
    int   buf  = 0;

    for (int t = 0; t < T; ++t) {
        float ns = wnum_s[(b * T + t) * 64 + lane];
        float ds = wden_s[(b * T + t) * 64 + lane];
        #pragma unroll 1
        for (int u = 0; u < 6; ++u) {
            float num = 0.0f, den = 0.0f;
            #pragma unroll
            for (int ii = 0; ii < 8; ++ii) {
                // wave-uniform lane index -> v_readlane (SGPR, no DS traffic)
                float vi = __uint_as_float(
                    __builtin_amdgcn_readlane(__float_as_uint(v), 8 * p + ii));
                float arg = fmaf(vi, nsg[ii], musig[ii]);
                float e   = __expf(arg);
                float s   = __builtin_amdgcn_rcpf(1.0f + e);
                den = fmaf(wvv[ii], s, den);
                num = fmaf(wev[ii], s, num);
            }
            pnd[buf][p][lane] = make_float2(num, den);
            __syncthreads();
            float wn = ns, wd = ds;
            #pragma unroll
            for (int q = 0; q < 8; ++q) {
                float2 pq = pnd[buf][q][lane];
                wn += pq.x; wd += pq.y;
            }
            v = (fmaf(cmt, v, glvl) + wn) *
                __builtin_amdgcn_rcpf(cmt + gl + wd + 1e-8f);
            buf ^= 1;
        }
        if (tid < 3) out[(b * T + t) * 3 + tid] = v;
    }
}

// ---------------------------------------------------------------------------
// Launch
// ---------------------------------------------------------------------------
extern "C" void kernel_launch(void* const* d_in, const int* in_sizes, int n_in,
                              void* d_out, int out_size, void* d_ws, size_t ws_size,
                              hipStream_t stream)
{
    (void)in_sizes; (void)n_in; (void)out_size; (void)ws_size;

    const float* x    = (const float*)d_in[0];
    const float* w1   = (const float*)d_in[1];
    const float* b1   = (const float*)d_in[2];
    const float* w2   = (const float*)d_in[3];
    const float* b2   = (const float*)d_in[4];
    const float* w3   = (const float*)d_in[5];
    const float* b3   = (const float*)d_in[6];
    const float* w4   = (const float*)d_in[7];
    const float* b4   = (const float*)d_in[8];
    const float* w5   = (const float*)d_in[9];
    const float* b5   = (const float*)d_in[10];
    const float* fcw  = (const float*)d_in[11];
    const float* fcb  = (const float*)d_in[12];
    const float* smu  = (const float*)d_in[13];
    const float* ssig = (const float*)d_in[14];
    const float* sw   = (const float*)d_in[15];
    const float* serv = (const float*)d_in[16];
    const float* mu   = (const float*)d_in[17];
    const float* sig  = (const float*)d_in[18];
    const float* ww   = (const float*)d_in[19];
    const float* erev = (const float*)d_in[20];
    const float* gl   = (const float*)d_in[21];
    const float* vl   = (const float*)d_in[22];
    const float* cm   = (const float*)d_in[23];
    float* out = (float*)d_out;

    const int BT = 512;

    char* wsB = (char*)d_ws;
    size_t off = 0;
    f16*   h1T  = (f16*)(wsB + off); off += (size_t)512 * 31 * 2368 * 2;   // 75.2 MB
    f16*   Wpk  = (f16*)(wsB + off); off += 65536;
    f16*   h2f  = (f16*)(wsB + off); off += (size_t)512 * 3374 * 16;       // 27.6 MB
    f16*   Wpk3 = (f16*)(wsB + off); off += 48 * 1032 * 2;
    f16*   Wpk1 = (f16*)(wsB + off); off += 32 * 136 * 2;
    float* h3   = (float*)(wsB + off); off += (size_t)512 * 48 * 5 * 22 * 4;
    float* h4   = (float*)(wsB + off); off += (size_t)512 * 64 * 3 * 20 * 4;
    float* h5   = (float*)(wsB + off); off += (size_t)512 * 64 * 18 * 4;
    float* feat = (float*)(wsB + off); off += (size_t)BT * 128 * 4;
    float* wnum = (float*)(wsB + off); off += (size_t)BT * 64 * 4;
    float* wden = (float*)(wsB + off); off += (size_t)BT * 64 * 4;

    wpack_all<<<327, 256, 0, stream>>>(w1, Wpk1, w2, Wpk, w3, Wpk3);
    conv1_mfma<<<1024, 512, 0, stream>>>(x, Wpk1, b1, h1T);
    conv2_mfma<<<512, 384, 0, stream>>>(h1T, Wpk, b2, h2f);
    conv3_mfma<<<512, 384, 0, stream>>>(h2f, Wpk3, b3, h3);

    // conv4: [512,48,5,22] -> [512,64,3,20]
    {
        int n_cg = 16, n_wg = 5;
        int sp_threads = BT * 3 * n_wg;
        int grid = (sp_threads + 255) / 256 * n_cg;
        conv_tile_kernel<48, 3, 3, 1, 4, 4><<<grid, 256, 0, stream>>>(
            h3, w4, b4, h4, 64, 5, 22, 3, 20, n_cg, n_wg, BT);
    }
    // conv5: -> [512,64,1,18]
    {
        int n_cg = 16, n_wg = 6;
        int sp_threads = BT * 1 * n_wg;
        int grid = (sp_threads + 255) / 256 * n_cg;
        conv_tile_kernel<64, 3, 3, 1, 4, 3><<<grid, 256, 0, stream>>>(
            h4, w5, b5, h5, 64, 3, 20, 1, 18, n_cg, n_wg, BT);
    }
    fc_relu_kernel<<<512, 256, 0, stream>>>(h5, fcw, fcb, feat);
    sensory_kernel<<<BT, 64, 0, stream>>>(feat, smu, ssig, sw, serv, wnum, wden);
    ltc_wave_kernel<<<32, 512, 0, stream>>>(wnum, wden, mu, sig, ww, erev,
                                            gl, vl, cm, out, 16);
}

// Round 18
// 245.111 us; speedup vs baseline: 1.0108x; 1.0108x over previous
//
#include <hip/hip_runtime.h>
#include <hip/hip_bf16.h>

// ---------------------------------------------------------------------------
// NCP model: conv head + FC + LTC recurrence.
// Round 17: final revert to R15's best measured configuration (245.5us).
//           R16's readlane experiment regressed LTC (52.8 -> 55.5us): the
//           8-deep readlane VALU->SGPR chain serializes where ds_bpermute
//           pipelines. LTC restored to the __shfl form. All conv/fc/sensory
//           kernels identical to R15.
// ---------------------------------------------------------------------------

typedef _Float16 f16;
typedef _Float16 f16x8 __attribute__((ext_vector_type(8)));
typedef _Float16 f16x4 __attribute__((ext_vector_type(4)));
typedef float    f32x4 __attribute__((ext_vector_type(4)));
typedef unsigned int u32;

static __device__ __forceinline__ float sigmoidf_fast(float x) {
    return __builtin_amdgcn_rcpf(1.0f + __expf(-x));
}

// async 16B global->LDS: LDS dest must be wave-uniform base + lane*16.
static __device__ __forceinline__ void gload_lds16(const void* g, void* l) {
    __builtin_amdgcn_global_load_lds(
        (const __attribute__((address_space(1))) void*)g,
        (__attribute__((address_space(3))) void*)l, 16, 0, 0);
}

// ---------------------------------------------------------------------------
// h1T layout: [512][31 rows][296 slots][8 halves] f16 (rows of 98 cols, 3 c8):
//   slot(w,c8) = c8*98 + (w&1)*49 + (w>>1)
// h2f layout: [512][14 rows][241 slots][8 halves] f16 (47 cols, 5 c8):
//   slot(w,c8) = c8*47 + (w&1)*24 + (w>>1)
// ---------------------------------------------------------------------------

// All three weight packs in one launch.
__global__ __launch_bounds__(256)
void wpack_all(const float* __restrict__ w1, f16* __restrict__ Wpk1,
               const float* __restrict__ w2, f16* __restrict__ Wpk,
               const float* __restrict__ w3, f16* __restrict__ Wpk3)
{
    int bx = blockIdx.x;
    if (bx < 17) {
        int idx = bx * 256 + threadIdx.x;
        if (idx >= 32 * 136) return;
        int co = idx / 136, kk = idx % 136;
        float v = 0.0f;
        if (co < 24 && kk < 120) {
            int p = kk >> 3, jj = kk & 7;
            int kh = p / 3, kwp = p % 3;
            int kws = jj >> 2, ci = jj & 3;
            int kw = 2 * kwp + kws;
            if (kw < 5 && ci < 3)
                v = w1[(((size_t)co * 3 + ci) * 5 + kh) * 5 + kw];
        }
        Wpk1[idx] = (f16)v;
    } else if (bx < 133) {
        int idx = (bx - 17) * 256 + threadIdx.x;
        if (idx >= 48 * 616) return;
        int co = idx / 616, kk = idx % 616;
        float v = 0.0f;
        if (kk < 608 && co < 36) {
            int c = kk >> 3, j = kk & 7;
            if (c < 75) {
                int pq = c / 3, c8 = c - 3 * pq;
                int kh = pq / 5, kw = pq - 5 * kh;
                int ci = c8 * 8 + j;
                v = w2[(((size_t)co * 24 + ci) * 5 + kh) * 5 + kw];
            }
        }
        Wpk[idx] = (f16)v;
    } else {
        int idx = (bx - 133) * 256 + threadIdx.x;
        if (idx >= 48 * 1032) return;
        int co = idx / 1032, kk = idx % 1032;
        float v = 0.0f;
        if (kk < 1024) {
            int c = kk >> 3, j = kk & 7;
            int pq = c / 5, c8 = c - 5 * pq;
            if (pq < 25) {
                int kh = pq / 5, kw = pq - 5 * kh;
                int ci = c8 * 8 + j;
                if (ci < 36)
                    v = w3[(((size_t)co * 36 + ci) * 5 + kh) * 5 + kw];
            }
        }
        Wpk3[idx] = (f16)v;
    }
}

// conv1 via MFMA: 2 blocks per image (ho halves). Staged rows [35][200][ci4]
// f16 in LDS (56 KB -> 2 blocks/CU). Weights in registers from global.
__global__ __launch_bounds__(512)
void conv1_mfma(const float* __restrict__ x, const f16* __restrict__ Wpk1,
                const float* __restrict__ b1, f16* __restrict__ h1T)
{
    __shared__ __align__(16) f16 img[35 * 200 * 4];   // 56,000 B

    int blk  = blockIdx.x;
    int m    = blk >> 1;
    int hf   = blk & 1;
    int tid  = threadIdx.x;
    int lane = tid & 63;
    int wv   = tid >> 6;        // 0..7
    int col  = lane & 15;
    int row4 = lane >> 4;

    int ho_base = hf * 16;
    int r0      = 2 * ho_base;
    int nrows   = hf ? 33 : 35;
    int nho     = hf ? 15 : 16;
    int npx     = nho * 98;
    int ntile   = (npx + 15) >> 4;
    int niter   = (ntile + 7) >> 3;

    // stage: batched preload, all loads in flight before writes
    {
        const float* p0 = x + (size_t)m * 39600 + (size_t)r0 * 200;
        int n4 = (nrows * 200) >> 2;
        float4 ra[4], rb[4], rc[4];
        #pragma unroll
        for (int k = 0; k < 4; ++k) {
            int u4 = tid + k * 512;
            if (u4 < n4) {
                ra[k] = *(const float4*)(p0 + (size_t)u4 * 4);
                rb[k] = *(const float4*)(p0 + 13200 + (size_t)u4 * 4);
                rc[k] = *(const float4*)(p0 + 26400 + (size_t)u4 * 4);
            }
        }
        #pragma unroll
        for (int k = 0; k < 4; ++k) {
            int u4 = tid + k * 512;
            if (u4 < n4) {
                float4 a = ra[k], b = rb[k], c = rc[k];
                f16x8 lo = { (f16)a.x, (f16)b.x, (f16)c.x, (f16)0.0f,
                             (f16)a.y, (f16)b.y, (f16)c.y, (f16)0.0f };
                f16x8 hi = { (f16)a.z, (f16)b.z, (f16)c.z, (f16)0.0f,
                             (f16)a.w, (f16)b.w, (f16)c.w, (f16)0.0f };
                *(f16x8*)(&img[(size_t)u4 * 16])     = lo;
                *(f16x8*)(&img[(size_t)u4 * 16 + 8]) = hi;
            }
        }
    }

    f16x8 af[2][4];
    #pragma unroll
    for (int Mt = 0; Mt < 2; ++Mt)
        #pragma unroll
        for (int t = 0; t < 4; ++t)
            af[Mt][t] = *(const f16x8*)((const char*)Wpk1 +
                           (Mt * 16 + col) * 272 + t * 64 + row4 * 16);

    int rowB[4], kwpv[4];
    #pragma unroll
    for (int t = 0; t < 4; ++t) {
        int p = 4 * t + row4; if (p > 14) p = 14;
        rowB[t] = (p / 3) * 1600;
        kwpv[t] = (p % 3) * 16;
    }

    float bvv[2][4];
    #pragma unroll
    for (int Mt = 0; Mt < 2; ++Mt)
        #pragma unroll
        for (int i = 0; i < 4; ++i) {
            int co = Mt * 16 + row4 * 4 + i;
            bvv[Mt][i] = (co < 24) ? b1[co] : 0.0f;
        }

    __syncthreads();

    const char* ic = (const char*)img;
    for (int it = 0; it < niter; ++it) {
        int s = wv + it * 8;
        if (s >= ntile) continue;
        int px = s * 16 + col;
        bool pv = (px < npx);
        int pc = pv ? px : npx - 1;
        int ho_l = pc / 98;
        int wo   = pc - ho_l * 98;
        int base = ho_l * 3200 + wo * 16;

        f32x4 a0 = {0.f,0.f,0.f,0.f}, a1 = {0.f,0.f,0.f,0.f};
        #pragma unroll
        for (int t = 0; t < 4; ++t) {
            f16x8 xf = *(const f16x8*)(ic + base + rowB[t] + kwpv[t]);
            a0 = __builtin_amdgcn_mfma_f32_16x16x32_f16(af[0][t], xf, a0, 0, 0, 0);
            a1 = __builtin_amdgcn_mfma_f32_16x16x32_f16(af[1][t], xf, a1, 0, 0, 0);
        }

        if (pv) {
            int ho = ho_base + ho_l;
            size_t rowbase = ((size_t)m * 31 + ho) * 296;
            int par = (wo & 1) * 49, wh = wo >> 1;
            int j0 = (row4 & 1) * 4;
            {
                int c8 = row4 >> 1;
                f16x4 pk = { (f16)fmaxf(a0[0] + bvv[0][0], 0.0f),
                             (f16)fmaxf(a0[1] + bvv[0][1], 0.0f),
                             (f16)fmaxf(a0[2] + bvv[0][2], 0.0f),
                             (f16)fmaxf(a0[3] + bvv[0][3], 0.0f) };
                int sl = c8 * 98 + par + wh;
                *(f16x4*)(h1T + (rowbase + sl) * 8 + j0) = pk;
            }
            if (row4 < 2) {
                f16x4 pk = { (f16)fmaxf(a1[0] + bvv[1][0], 0.0f),
                             (f16)fmaxf(a1[1] + bvv[1][1], 0.0f),
                             (f16)fmaxf(a1[2] + bvv[1][2], 0.0f),
                             (f16)fmaxf(a1[3] + bvv[1][3], 0.0f) };
                int sl = 2 * 98 + par + wh;
                *(f16x4*)(h1T + (rowbase + sl) * 8 + j0) = pk;
            }
        }
    }
}

// conv2 via MFMA: block = one image, whole image in LDS via async
// global_load_lds. A in registers; B parity layout.
__global__ __launch_bounds__(384)
void conv2_mfma(const f16* __restrict__ h1T, const f16* __restrict__ Wpk,
                const float* __restrict__ b2, f16* __restrict__ h2f)
{
    __shared__ __align__(16) f16 img[9216 * 8];   // 147,456 B (9176 used)
    __shared__ u32 lutS[76];

    int m    = blockIdx.x;
    int tid  = threadIdx.x;
    int lane = tid & 63;
    int wv   = tid >> 6;
    int ct   = wv >> 1;
    int sh   = wv & 1;
    int row4 = lane >> 4;
    int col  = lane & 15;

    {
        const char* g = (const char*)(h1T + (size_t)m * 73408);
        char* l = (char*)img;
        #pragma unroll
        for (int k = 0; k < 24; ++k) {
            int u0 = wv * 64 + k * 384;
            gload_lds16(g + ((size_t)(u0 + lane)) * 16, l + (size_t)u0 * 16);
        }
    }

    if (tid < 76) {
        int c = tid; u32 v = 0;
        if (c < 75) {
            int pq = c / 3, c8 = c - 3 * pq;
            int kh = pq / 5, kw = pq - 5 * kh;
            u32 ofs = (u32)(c8 * 98 + (kw & 1) * 49 + (kw >> 1));
            v = ((u32)(kh * 4736) << 8) | ofs;
        }
        lutS[c] = v;
    }

    f16x8 af[19];
    {
        const char* wb = (const char*)Wpk + (size_t)(ct * 16 + col) * 1232 + row4 * 16;
        #pragma unroll
        for (int t = 0; t < 19; ++t)
            af[t] = *(const f16x8*)(wb + t * 64);
    }

    float bv[4];
    #pragma unroll
    for (int i = 0; i < 4; ++i) {
        int co = ct * 16 + row4 * 4 + i;
        bv[i] = (co < 36) ? b2[co] : 0.0f;
    }
    int c8o  = ct * 2 + (row4 >> 1);
    int hsel = (row4 & 1) * 4;

    __syncthreads();

    const char* ic = (const char*)img;
    for (int it = 0; it < 7; ++it) {
        int rbase[3], valid[3], hov[3], wov[3];
        #pragma unroll
        for (int si = 0; si < 3; ++si) {
            int tile = sh * 21 + it * 3 + si;
            int px   = tile * 16 + col;
            valid[si] = (px < 658);
            int pc = valid[si] ? px : 657;
            int ho = pc / 47;
            int wo = pc - 47 * ho;
            rbase[si] = ho * 9472 + wo * 16;
            hov[si] = ho; wov[si] = wo;
        }

        f32x4 acc0 = {0.f,0.f,0.f,0.f}, acc1 = {0.f,0.f,0.f,0.f}, acc2 = {0.f,0.f,0.f,0.f};
        #pragma unroll
        for (int t = 0; t < 19; ++t) {
            u32 lv   = lutS[4 * t + row4];
            int rowb = (int)(lv >> 8);
            int boff = (int)(lv & 255) << 4;
            f16x8 a = af[t];
            {
                f16x8 xf = *(const f16x8*)(ic + rbase[0] + rowb + boff);
                acc0 = __builtin_amdgcn_mfma_f32_16x16x32_f16(a, xf, acc0, 0, 0, 0);
            }
            {
                f16x8 xf = *(const f16x8*)(ic + rbase[1] + rowb + boff);
                acc1 = __builtin_amdgcn_mfma_f32_16x16x32_f16(a, xf, acc1, 0, 0, 0);
            }
            {
                f16x8 xf = *(const f16x8*)(ic + rbase[2] + rowb + boff);
                acc2 = __builtin_amdgcn_mfma_f32_16x16x32_f16(a, xf, acc2, 0, 0, 0);
            }
        }

        #pragma unroll
        for (int si = 0; si < 3; ++si) {
            f32x4 a = (si == 0) ? acc0 : (si == 1) ? acc1 : acc2;
            if (valid[si] && c8o < 5) {
                int wo = wov[si], ho = hov[si];
                f16x4 pk;
                #pragma unroll
                for (int i = 0; i < 4; ++i) pk[i] = (f16)fmaxf(a[i] + bv[i], 0.0f);
                int sl = c8o * 47 + (wo & 1) * 24 + (wo >> 1);
                *(f16x4*)(h2f + ((size_t)m * 3374 + (size_t)ho * 241 + sl) * 8 + hsel) = pk;
            }
        }
    }
}

// conv3 via MFMA: whole image + weights in LDS via async global_load_lds.
__global__ __launch_bounds__(384)
void conv3_mfma(const f16* __restrict__ h2f, const f16* __restrict__ Wpk3,
                const float* __restrict__ b3, float* __restrict__ h3)
{
    __shared__ __align__(16) f16 Wl[6208 * 8];    // 99,328 B (99,072 used)
    __shared__ __align__(16) f16 img[3392 * 8];   // 54,272 B (53,984 used)
    __shared__ u32 lut[128];

    int m    = blockIdx.x;
    int tid  = threadIdx.x;
    int lane = tid & 63;
    int wv   = tid >> 6;
    int ct   = wv >> 1;
    int sh   = wv & 1;
    int row4 = lane >> 4;
    int col  = lane & 15;

    {
        const char* g = (const char*)Wpk3;
        char* l = (char*)Wl;
        #pragma unroll
        for (int k = 0; k < 17; ++k) {
            int u0 = wv * 64 + k * 384;
            if (u0 < 6208)
                gload_lds16(g + ((size_t)(u0 + lane)) * 16, l + (size_t)u0 * 16);
        }
    }
    {
        const char* g = (const char*)(h2f + (size_t)m * 3374 * 8);
        char* l = (char*)img;
        #pragma unroll
        for (int k = 0; k < 9; ++k) {
            int u0 = wv * 64 + k * 384;
            if (u0 < 3392)
                gload_lds16(g + ((size_t)(u0 + lane)) * 16, l + (size_t)u0 * 16);
        }
    }

    if (tid < 128) {
        int c  = tid;
        int pq = c / 5, c8 = c - 5 * pq;
        int kh = pq / 5, kw = pq - 5 * kh;
        lut[c] = ((u32)(kh * 3856) << 8) |
                 (u32)(c8 * 47 + (kw & 1) * 24 + (kw >> 1));
    }

    int rb[4], wo16[4], valid[4], hov[4], wov[4];
    int nsi = 4 - sh;
    #pragma unroll
    for (int si = 0; si < 4; ++si) {
        int s  = 4 * sh + si;
        int px = 16 * s + col;
        valid[si] = (si < nsi) && (px < 110);
        int pc = px < 110 ? px : 109;
        int ho = pc / 22, wo = pc - 22 * ho;
        rb[si]   = ho * 7712;
        wo16[si] = wo * 16;
        hov[si]  = ho; wov[si] = wo;
    }

    float bv[4];
    #pragma unroll
    for (int i = 0; i < 4; ++i) bv[i] = b3[ct * 16 + row4 * 4 + i];

    __syncthreads();

    int Abase = (ct * 16 + col) * 2064 + row4 * 16;
    const char* Wc = (const char*)Wl;
    const char* ic = (const char*)img;

    f32x4 a0 = {0.f,0.f,0.f,0.f}, a1 = {0.f,0.f,0.f,0.f};
    f32x4 a2 = {0.f,0.f,0.f,0.f}, a3 = {0.f,0.f,0.f,0.f};
    #pragma unroll 8
    for (int t = 0; t < 32; ++t) {
        u32 lv     = lut[4 * t + row4];
        int rowoff = (int)(lv >> 8);
        int boff   = (int)(lv & 255) << 4;
        f16x8 af = *(const f16x8*)(Wc + Abase + 64 * t);
        {
            f16x8 xf = *(const f16x8*)(ic + rb[0] + rowoff + boff + wo16[0]);
            a0 = __builtin_amdgcn_mfma_f32_16x16x32_f16(af, xf, a0, 0, 0, 0);
        }
        {
            f16x8 xf = *(const f16x8*)(ic + rb[1] + rowoff + boff + wo16[1]);
            a1 = __builtin_amdgcn_mfma_f32_16x16x32_f16(af, xf, a1, 0, 0, 0);
        }
        {
            f16x8 xf = *(const f16x8*)(ic + rb[2] + rowoff + boff + wo16[2]);
            a2 = __builtin_amdgcn_mfma_f32_16x16x32_f16(af, xf, a2, 0, 0, 0);
        }
        {
            f16x8 xf = *(const f16x8*)(ic + rb[3] + rowoff + boff + wo16[3]);
            a3 = __builtin_amdgcn_mfma_f32_16x16x32_f16(af, xf, a3, 0, 0, 0);
        }
    }

    int co0 = ct * 16 + row4 * 4;
    #pragma unroll
    for (int si = 0; si < 4; ++si) {
        if (!valid[si]) continue;
        f32x4 a = (si == 0) ? a0 : (si == 1) ? a1 : (si == 2) ? a2 : a3;
        float* op = h3 + (((size_t)m * 48 + co0) * 5 + hov[si]) * 22 + wov[si];
        #pragma unroll
        for (int i = 0; i < 4; ++i)
            op[(size_t)i * 110] = fmaxf(a[i] + bv[i], 0.0f);
    }
}

// Register-tiled fp32 direct conv for conv4..conv5.
template<int CIN, int KH, int KW, int STRIDE, int CO_T, int WO_T>
__global__ __launch_bounds__(256)
void conv_tile_kernel(const float* __restrict__ in, const float* __restrict__ wt,
                      const float* __restrict__ bias, float* __restrict__ out,
                      int Cout, int Hin, int Win, int Hout, int Wout,
                      int n_cg, int n_wg, int M)
{
    constexpr int LOAD_W = (WO_T - 1) * STRIDE + KW;

    int bx = blockIdx.x;
    int cg = bx % n_cg;
    int gid = (bx / n_cg) * blockDim.x + threadIdx.x;
    int wg = gid % n_wg;
    int t  = gid / n_wg;
    int ho = t % Hout;
    int m  = t / Hout;
    if (m >= M) return;

    int wo0 = wg * WO_T;
    int co0 = cg * CO_T;

    const float* ip = in + ((size_t)(m * CIN) * Hin + (size_t)ho * STRIDE) * Win
                         + (size_t)wo0 * STRIDE;
    const float* wp = wt + (size_t)co0 * (CIN * KH * KW);

    float acc[CO_T][WO_T];
    #pragma unroll
    for (int c = 0; c < CO_T; ++c) {
        float b = bias[co0 + c];
        #pragma unroll
        for (int q = 0; q < WO_T; ++q) acc[c][q] = b;
    }

    #pragma unroll 1
    for (int ci = 0; ci < CIN; ++ci) {
        #pragma unroll
        for (int kh = 0; kh < KH; ++kh) {
            const float* row = ip + ((size_t)ci * Hin + kh) * Win;
            float xv[LOAD_W];
            #pragma unroll
            for (int l = 0; l < LOAD_W; ++l) xv[l] = row[l];
            const float* wrow = wp + (ci * KH + kh) * KW;
            #pragma unroll
            for (int c = 0; c < CO_T; ++c) {
                #pragma unroll
                for (int kw = 0; kw < KW; ++kw) {
                    float wv = wrow[c * (CIN * KH * KW) + kw];
                    #pragma unroll
                    for (int q = 0; q < WO_T; ++q)
                        acc[c][q] = fmaf(xv[q * STRIDE + kw], wv, acc[c][q]);
                }
            }
        }
    }

    #pragma unroll
    for (int c = 0; c < CO_T; ++c) {
        float* op = out + (((size_t)m * Cout + co0 + c) * Hout + ho) * Wout + wo0;
        #pragma unroll
        for (int q = 0; q < WO_T; ++q) {
            if (wo0 + q < Wout) op[q] = fmaxf(acc[c][q], 0.0f);
        }
    }
}

// FC (1152 -> 128) + relu. One frame per block, 8-way split-K, float4 loads.
__global__ __launch_bounds__(256)
void fc_relu_kernel(const float* __restrict__ h, const float* __restrict__ w,
                    const float* __restrict__ b, float* __restrict__ out)
{
    __shared__ float hs[1152];
    __shared__ float part[8][32][4];
    int f   = blockIdx.x;
    int tid = threadIdx.x;
    int ks  = tid >> 5;
    int j4  = tid & 31;
    for (int k = tid; k < 1152; k += 256) hs[k] = h[(size_t)f * 1152 + k];
    __syncthreads();
    const float4* w4 = (const float4*)w;
    float4 acc = {0.f, 0.f, 0.f, 0.f};
    int k0 = ks * 144;
    #pragma unroll 4
    for (int kk = 0; kk < 144; ++kk) {
        int k = k0 + kk;
        float4 wv = w4[(size_t)k * 32 + j4];
        float hb = hs[k];
        acc.x = fmaf(wv.x, hb, acc.x);
        acc.y = fmaf(wv.y, hb, acc.y);
        acc.z = fmaf(wv.z, hb, acc.z);
        acc.w = fmaf(wv.w, hb, acc.w);
    }
    *(float4*)&part[ks][j4][0] = acc;
    __syncthreads();
    if (tid < 128) {
        int j = tid, jq = j >> 2, r = j & 3;
        float s = b[j];
        #pragma unroll
        for (int q = 0; q < 8; ++q) s += part[q][jq][r];
        out[(size_t)f * 128 + j] = fmaxf(s, 0.0f);
    }
}

// Sensory synapse pre-computation.
__global__ __launch_bounds__(64)
void sensory_kernel(const float* __restrict__ feat,
                    const float* __restrict__ s_mu,
                    const float* __restrict__ s_sigma,
                    const float* __restrict__ s_w,
                    const float* __restrict__ s_erev,
                    float* __restrict__ wnum, float* __restrict__ wden)
{
    __shared__ float y[128];
    int bt = blockIdx.x;
    int n  = threadIdx.x;
    for (int s = n; s < 128; s += 64) y[s] = feat[bt * 128 + s];
    __syncthreads();
    float num = 0.0f, den = 0.0f;
    for (int s = 0; s < 128; ++s) {
        int o = s * 64 + n;
        float a = s_w[o] * sigmoidf_fast((y[s] - s_mu[o]) * s_sigma[o]);
        num = fmaf(a, s_erev[o], num);
        den += a;
    }
    wnum[bt * 64 + n] = num;
    wden[bt * 64 + n] = den;
}

// LTC recurrence — R10/R15's empirically-best form (52.8us measured):
// 8 waves/512 thr per batch, matrix in registers, __shfl broadcast,
// one barrier per unfold, double-buffered partials.
__global__ __launch_bounds__(512)
void ltc_wave_kernel(const float* __restrict__ wnum_s,
                     const float* __restrict__ wden_s,
                     const float* __restrict__ mu, const float* __restrict__ sigma,
                     const float* __restrict__ w, const float* __restrict__ erev,
                     const float* __restrict__ gleak, const float* __restrict__ vleak,
                     const float* __restrict__ cm, float* __restrict__ out, int T)
{
    __shared__ float2 pnd[2][8][64];

    int b    = blockIdx.x;
    int tid  = threadIdx.x;
    int lane = tid & 63;
    int p    = tid >> 6;

    float musig[8], nsg[8], wvv[8], wev[8];
    #pragma unroll
    for (int ii = 0; ii < 8; ++ii) {
        int o = (8 * p + ii) * 64 + lane;
        float sg = sigma[o];
        musig[ii] = mu[o] * sg;
        nsg[ii]   = -sg;
        float wl  = w[o];
        wvv[ii]   = wl;
        wev[ii]   = wl * erev[o];
    }
    float gl   = gleak[lane];
    float glvl = gl * vleak[lane];
    float cmt  = cm[lane] * 6.0f;
    float v    = 0.0f;
    int   buf  = 0;

    for (int t = 0; t < T; ++t) {
        float ns = wnum_s[(b * T + t) * 64 + lane];
        float ds = wden_s[(b * T + t) * 64 + lane];
        #pragma unroll 1
        for (int u = 0; u < 6; ++u) {
            float num = 0.0f, den = 0.0f;
            #pragma unroll
            for (int ii = 0; ii < 8; ++ii) {
                float vi  = __shfl(v, 8 * p + ii);
                float arg = fmaf(vi, nsg[ii], musig[ii]);
                float e   = __expf(arg);
                float s   = __builtin_amdgcn_rcpf(1.0f + e);
                den = fmaf(wvv[ii], s, den);
                num = fmaf(wev[ii], s, num);
            }
            pnd[buf][p][lane] = make_float2(num, den);
            __syncthreads();
            float wn = ns, wd = ds;
            #pragma unroll
            for (int q = 0; q < 8; ++q) {
                float2 pq = pnd[buf][q][lane];
                wn += pq.x; wd += pq.y;
            }
            v = (fmaf(cmt, v, glvl) + wn) *
                __builtin_amdgcn_rcpf(cmt + gl + wd + 1e-8f);
            buf ^= 1;
        }
        if (tid < 3) out[(b * T + t) * 3 + tid] = v;
    }
}

// ---------------------------------------------------------------------------
// Launch
// ---------------------------------------------------------------------------
extern "C" void kernel_launch(void* const* d_in, const int* in_sizes, int n_in,
                              void* d_out, int out_size, void* d_ws, size_t ws_size,
                              hipStream_t stream)
{
    (void)in_sizes; (void)n_in; (void)out_size; (void)ws_size;

    const float* x    = (const float*)d_in[0];
    const float* w1   = (const float*)d_in[1];
    const float* b1   = (const float*)d_in[2];
    const float* w2   = (const float*)d_in[3];
    const float* b2   = (const float*)d_in[4];
    const float* w3   = (const float*)d_in[5];
    const float* b3   = (const float*)d_in[6];
    const float* w4   = (const float*)d_in[7];
    const float* b4   = (const float*)d_in[8];
    const float* w5   = (const float*)d_in[9];
    const float* b5   = (const float*)d_in[10];
    const float* fcw  = (const float*)d_in[11];
    const float* fcb  = (const float*)d_in[12];
    const float* smu  = (const float*)d_in[13];
    const float* ssig = (const float*)d_in[14];
    const float* sw   = (const float*)d_in[15];
    const float* serv = (const float*)d_in[16];
    const float* mu   = (const float*)d_in[17];
    const float* sig  = (const float*)d_in[18];
    const float* ww   = (const float*)d_in[19];
    const float* erev = (const float*)d_in[20];
    const float* gl   = (const float*)d_in[21];
    const float* vl   = (const float*)d_in[22];
    const float* cm   = (const float*)d_in[23];
    float* out = (float*)d_out;

    const int BT = 512;

    char* wsB = (char*)d_ws;
    size_t off = 0;
    f16*   h1T  = (f16*)(wsB + off); off += (size_t)512 * 31 * 2368 * 2;   // 75.2 MB
    f16*   Wpk  = (f16*)(wsB + off); off += 65536;
    f16*   h2f  = (f16*)(wsB + off); off += (size_t)512 * 3374 * 16;       // 27.6 MB
    f16*   Wpk3 = (f16*)(wsB + off); off += 48 * 1032 * 2;
    f16*   Wpk1 = (f16*)(wsB + off); off += 32 * 136 * 2;
    float* h3   = (float*)(wsB + off); off += (size_t)512 * 48 * 5 * 22 * 4;
    float* h4   = (float*)(wsB + off); off += (size_t)512 * 64 * 3 * 20 * 4;
    float* h5   = (float*)(wsB + off); off += (size_t)512 * 64 * 18 * 4;
    float* feat = (float*)(wsB + off); off += (size_t)BT * 128 * 4;
    float* wnum = (float*)(wsB + off); off += (size_t)BT * 64 * 4;
    float* wden = (float*)(wsB + off); off += (size_t)BT * 64 * 4;

    wpack_all<<<327, 256, 0, stream>>>(w1, Wpk1, w2, Wpk, w3, Wpk3);
    conv1_mfma<<<1024, 512, 0, stream>>>(x, Wpk1, b1, h1T);
    conv2_mfma<<<512, 384, 0, stream>>>(h1T, Wpk, b2, h2f);
    conv3_mfma<<<512, 384, 0, stream>>>(h2f, Wpk3, b3, h3);

    // conv4: [512,48,5,22] -> [512,64,3,20]
    {
        int n_cg = 16, n_wg = 5;
        int sp_threads = BT * 3 * n_wg;
        int grid = (sp_threads + 255) / 256 * n_cg;
        conv_tile_kernel<48, 3, 3, 1, 4, 4><<<grid, 256, 0, stream>>>(
            h3, w4, b4, h4, 64, 5, 22, 3, 20, n_cg, n_wg, BT);
    }
    // conv5: -> [512,64,1,18]
    {
        int n_cg = 16, n_wg = 6;
        int sp_threads = BT * 1 * n_wg;
        int grid = (sp_threads + 255) / 256 * n_cg;
        conv_tile_kernel<64, 3, 3, 1, 4, 3><<<grid, 256, 0, stream>>>(
            h4, w5, b5, h5, 64, 3, 20, 1, 18, n_cg, n_wg, BT);
    }
    fc_relu_kernel<<<512, 256, 0, stream>>>(h5, fcw, fcb, feat);
    sensory_kernel<<<BT, 64, 0, stream>>>(feat, smu, ssig, sw, serv, wnum, wden);
    ltc_wave_kernel<<<32, 512, 0, stream>>>(wnum, wden, mu, sig, ww, erev,
                                            gl, vl, cm, out, 16);
}